// Round 1
// baseline (286.859 us; speedup 1.0000x reference)
//
#include <hip/hip_runtime.h>
#include <stdint.h>

// Problem constants (fixed by the reference file)
#define NPTS   4194304
#define IMG_H  1024
#define IMG_W  1280
#define NPIX   (IMG_H * IMG_W)

static const unsigned long long KEY_SENTINEL = ~0ULL;

// ---------------------------------------------------------------------------
// Kernel 1: init the z-buffer keys to sentinel (ws is poisoned to 0xAA each run)
// ---------------------------------------------------------------------------
__global__ void init_keys(unsigned long long* __restrict__ keys, int npix) {
    int i = blockIdx.x * blockDim.x + threadIdx.x;
    if (i < npix) keys[i] = KEY_SENTINEL;
}

// ---------------------------------------------------------------------------
// Kernel 2: project each point and atomicMin a packed (z_bits<<32 | index) key.
// Positive-float bit patterns are order-preserving as unsigned ints, so
// atomicMin picks min-z; ties resolve to min index == stable argsort winner.
// ---------------------------------------------------------------------------
__global__ void scatter_points(const float* __restrict__ points,
                               const float* __restrict__ Kmat,
                               const int* __restrict__ heightp,
                               const int* __restrict__ widthp,
                               unsigned long long* __restrict__ keys,
                               int n) {
    int i = blockIdx.x * blockDim.x + threadIdx.x;
    if (i >= n) return;

    float x = points[3 * i + 0];
    float y = points[3 * i + 1];
    float z = points[3 * i + 2];

    float fx = Kmat[0], cx = Kmat[2];
    float fy = Kmat[4], cy = Kmat[5];
    int   width  = widthp[0];
    int   height = heightp[0];

    // Match numpy bit-for-bit: IEEE f32 mul, div, add, round-half-even.
    float uf = rintf(fx * x / z + cx);
    float vf = rintf(fy * y / z + cy);

    bool valid = (z > 0.0f) &&
                 (uf >= 0.0f) && (uf < (float)width) &&
                 (vf >= 0.0f) && (vf < (float)height);
    if (!valid) return;

    int u = (int)uf;
    int v = (int)vf;
    int pix = v * width + u;

    unsigned int zbits = __float_as_uint(z);           // z > 0 => monotone bits
    unsigned long long key =
        ((unsigned long long)zbits << 32) | (unsigned int)i;
    atomicMin(&keys[pix], key);
}

// ---------------------------------------------------------------------------
// Kernel 3: resolve winners -> gather colors; zero where no point landed.
// ---------------------------------------------------------------------------
__global__ void resolve_pixels(const unsigned long long* __restrict__ keys,
                               const float* __restrict__ colors,
                               float* __restrict__ out,
                               int npix) {
    int i = blockIdx.x * blockDim.x + threadIdx.x;
    if (i >= npix) return;

    unsigned long long key = keys[i];
    float r = 0.0f, g = 0.0f, b = 0.0f;
    if (key != KEY_SENTINEL) {
        unsigned int idx = (unsigned int)(key & 0xFFFFFFFFu);
        r = colors[3 * idx + 0];
        g = colors[3 * idx + 1];
        b = colors[3 * idx + 2];
    }
    out[3 * i + 0] = r;
    out[3 * i + 1] = g;
    out[3 * i + 2] = b;
}

// ---------------------------------------------------------------------------
extern "C" void kernel_launch(void* const* d_in, const int* in_sizes, int n_in,
                              void* d_out, int out_size, void* d_ws, size_t ws_size,
                              hipStream_t stream) {
    const float* points = (const float*)d_in[0];   // (N,3)
    const float* colors = (const float*)d_in[1];   // (N,3)
    const float* Kmat   = (const float*)d_in[2];   // (3,3)
    const int*   hgt    = (const int*)d_in[3];     // scalar
    const int*   wid    = (const int*)d_in[4];     // scalar

    float* out = (float*)d_out;                    // (H,W,3) f32
    unsigned long long* keys = (unsigned long long*)d_ws;  // NPIX u64 = 10.5 MB

    int n = in_sizes[0] / 3;                       // number of points

    const int B = 256;
    init_keys<<<(NPIX + B - 1) / B, B, 0, stream>>>(keys, NPIX);
    scatter_points<<<(n + B - 1) / B, B, 0, stream>>>(points, Kmat, hgt, wid,
                                                      keys, n);
    resolve_pixels<<<(NPIX + B - 1) / B, B, 0, stream>>>(keys, colors, out, NPIX);
}